// Round 8
// baseline (258.186 us; speedup 1.0000x reference)
//
#include <hip/hip_runtime.h>
#include <hip/hip_bf16.h>

#define B_   16
#define K_   50
#define CIN  256
#define F_   76
#define A_   3
#define NCH  85
#define OC   255
#define HW   (F_*F_)
#define SLAB (F_*NCH)            // 6460 floats per (b,a,j)

// ws float layout
#define WS_BIAS_F 0              // 256 (conv_b padded)
#define WS_LAB_F  256            // 16*50*16 = 12800
#define WS_W15P_F 13056          // 256*16 = 4096
#define WS_B15_F  17152          // 16
#define WS_CNT_F  17168          // 1 (int)
#define WS_REC_F  17184          // 800*8 = 6400
#define WS_PART_F 23584          // 1536*8 = 12288
#define WS_OMV_F  35872          // 16*3*5776 = 277248
#define WS_END_F  313120         // 1.25 MB

#define NTL   46                 // 128-position tiles per batch (46*128 >= 5776)
#define NCONV (B_*NTL)           // 736
#define NREC  800
#define NROW  (NCONV + NREC)     // 1536

__device__ __constant__ float AW9[9] = {1.25f, 2.0f, 4.125f, 3.75f, 7.75f, 7.375f, 14.5f, 19.5f, 46.625f};
__device__ __constant__ float AH9[9] = {1.625f, 3.75f, 2.875f, 7.625f, 5.625f, 14.875f, 11.25f, 24.75f, 40.75f};

__device__ __forceinline__ float sigm(float r) { return 1.0f / (1.0f + __expf(-r)); }
__device__ __forceinline__ float bce_t(float p, float tv) {
    float pc = fminf(fmaxf(p, 1e-12f), 1.0f - 1e-7f);
    return -(tv * __logf(pc) + (1.0f - tv) * __logf(1.0f - pc));
}

// ---------------- prep ----------------
// labrec: A0={tx,ty,tw,th} A1={valid, fa(-1 if not pos), fi, fj} B0={txv,tyv,logw,logh} B1={sc,cls,0,0}
__global__ void prep_kernel(const float* __restrict__ conv_w, const float* __restrict__ conv_b,
                            const float* __restrict__ labels, float* __restrict__ ws) {
    int bid = blockIdx.x, t = threadIdx.x;
    if (bid == 0) {
        ws[WS_BIAS_F + t] = (t < OC) ? conv_b[t] : 0.0f;
    } else if (bid == 1) {
        for (int idx = t; idx < B_ * K_; idx += 256) {
            const float* L = labels + idx * 5;
            float cls = L[0], xc = L[1], yc = L[2], wl = L[3], hl = L[4];
            float ssum = cls + xc + yc + wl + hl;
            float validf = (ssum > 0.0f) ? 1.0f : 0.0f;
            float tx = xc * F_, ty = yc * F_, tw = wl * F_, th = hl * F_;
            int ii = (int)tx, jj = (int)ty;
            float tarea = tw * th;
            float best = -1.0f; int bn = 0;
            #pragma unroll
            for (int n = 0; n < 9; n++) {
                float inter = fminf(tw, AW9[n]) * fminf(th, AH9[n]);
                float iou = inter / (tarea + AW9[n] * AH9[n] - inter);
                if (iou > best) { best = iou; bn = n; }
            }
            int a = bn % 3;
            bool self = (validf != 0.0f) && (bn < 3);
            float* R = ws + WS_LAB_F + idx * 16;
            R[0] = tx; R[1] = ty; R[2] = tw; R[3] = th;
            R[4] = validf; R[5] = self ? (float)a : -1.0f; R[6] = (float)ii; R[7] = (float)jj;
            R[8] = tx - (float)ii; R[9] = ty - (float)jj;
            R[10] = __logf(tw / AW9[a] + 1e-16f);
            R[11] = __logf(th / AH9[a] + 1e-16f);
            R[12] = sqrtf(2.0f - tarea / (float)HW);
            R[13] = cls; R[14] = 0.0f; R[15] = 0.0f;
        }
    } else { // W15 padded f32 [c][16] + bias15 + counter reset
        for (int idx = t; idx < 4096; idx += 256) {
            int c = idx >> 4, r = idx & 15;
            float v = 0.0f;
            if (r < 15) v = conv_w[((r / 5) * NCH + (r % 5)) * CIN + c];
            ws[WS_W15P_F + idx] = v;
        }
        if (t < 16) ws[WS_B15_F + t] = (t < 15) ? conv_b[(t / 5) * NCH + (t % 5)] : 0.0f;
        if (t == 16) *(int*)(ws + WS_CNT_F) = 0;
    }
}

// ---------------- convloss: 4-way channel-split conv (regs) + per-(pos,anchor) losses ----------------
// Block = (b, tile of 128 positions); 512 threads; quarter q = t>>7 handles channels [64q,64q+64).
__global__ __launch_bounds__(512) void convloss_kernel(const float* __restrict__ xin,
                                                       float* __restrict__ ws) {
    __shared__ float4 LAB[K_ * 4];        // 3200 B
    __shared__ float accS[4][128][17];    // 34816 B (stride 17 -> conflict-free)
    __shared__ float redS[8][4];

    const int t = threadIdx.x;
    const int blk = blockIdx.x;
    const int b = blk / NTL, tile = blk - b * NTL;
    const int ph = t & 127;
    const int q  = t >> 7;                              // wave-pair uniform
    const int p0 = tile * 128 + ph;
    const int p = (p0 < HW) ? p0 : HW - 1;

    if (t < K_ * 4) LAB[t] = ((const float4*)(ws + WS_LAB_F + b * (K_ * 16)))[t];

    // ---- conv: this thread's 64-channel quarter, software-pipelined 8-wide ----
    const float* xp = xin + (size_t)b * CIN * HW + (size_t)q * 64 * HW + p;
    const float* Wp = ws + WS_W15P_F + q * 64 * 16;

    float acc[15];
    #pragma unroll
    for (int r = 0; r < 15; r++) acc[r] = 0.0f;

    float xv[8];
    #pragma unroll
    for (int u = 0; u < 8; u++) xv[u] = xp[(size_t)u * HW];
    #pragma unroll 1
    for (int c8 = 0; c8 < 8; c8++) {
        float xn[8];
        const int cnx = (c8 < 7) ? (c8 + 1) : 7;
        #pragma unroll
        for (int u = 0; u < 8; u++) xn[u] = xp[(size_t)(cnx * 8 + u) * HW];
        #pragma unroll
        for (int u = 0; u < 8; u++) {
            const float xvu = xv[u];
            const float* wrow = Wp + (c8 * 8 + u) * 16;   // uniform -> scalar loads
            #pragma unroll
            for (int r = 0; r < 15; r++) acc[r] = fmaf(xvu, wrow[r], acc[r]);
        }
        #pragma unroll
        for (int u = 0; u < 8; u++) xv[u] = xn[u];
    }

    #pragma unroll
    for (int r = 0; r < 15; r++) accS[q][ph][r] = acc[r];
    __syncthreads();

    // ---- loss phase: one (pos, anchor) cell per thread, t < 384 ----
    float lxy = 0.0f, lwh = 0.0f, lobj = 0.0f, l2 = 0.0f;
    if (t < 384) {
        const int a = t >> 7, pp = t & 127;
        const int pc = tile * 128 + pp;
        if (pc < HW) {
            float c5[5];
            #pragma unroll
            for (int r = 0; r < 5; r++)
                c5[r] = accS[0][pp][a * 5 + r] + accS[1][pp][a * 5 + r]
                      + accS[2][pp][a * 5 + r] + accS[3][pp][a * 5 + r]
                      + ws[WS_B15_F + a * 5 + r];
            const int j = pc / F_, i = pc - j * F_;
            const float fi_t = (float)i, fj_t = (float)j, fa_t = (float)a;
            const float X = sigm(c5[0]), Y = sigm(c5[1]);
            const float WR = c5[2], HR = c5[3], OB = sigm(c5[4]);
            const float PX = X + fi_t, PY = Y + fj_t;
            const float pw_ = __expf(WR) * AW9[a], ph_ = __expf(HR) * AH9[a];
            const float hpw = pw_ * 0.5f, hph = ph_ * 0.5f, arp = pw_ * ph_;

            float maxiou = 0.0f; int mk = -1;
            #pragma unroll 2
            for (int k = 0; k < K_; k++) {
                float4 A0 = LAB[4 * k], A1 = LAB[4 * k + 1];
                float tx = A0.x, ty = A0.y, tw = A0.z, th = A0.w;
                float tlx = fmaxf(PX - hpw, tx - tw * 0.5f);
                float tly = fmaxf(PY - hph, ty - th * 0.5f);
                float brx = fminf(PX + hpw, tx + tw * 0.5f);
                float bry = fminf(PY + hph, ty + th * 0.5f);
                float iw = brx - tlx, ih = bry - tly;
                float inter = (iw > 0.0f && ih > 0.0f) ? iw * ih : 0.0f;
                float iou = __fdividef(inter, arp + tw * th - inter);
                iou = (A1.x != 0.0f) ? iou : 0.0f;
                maxiou = fmaxf(maxiou, iou);
                bool match = (A1.y == fa_t) & (A1.z == fi_t) & (A1.w == fj_t);
                mk = match ? k : mk;
            }
            float objmask = (maxiou > 0.7f) ? 0.0f : 1.0f;
            float omv;
            if (mk >= 0) {
                float4 B0 = LAB[4 * mk + 2];
                float4 B1 = LAB[4 * mk + 3];
                float sc = B1.x, sc2 = sc * sc;
                lxy = (bce_t(X, B0.x) + bce_t(Y, B0.y)) * sc2;
                float dw = WR - B0.z, dh = HR - B0.w;
                lwh = 0.5f * sc2 * (dw * dw + dh * dh);
                float pco = fminf(fmaxf(OB, 1e-12f), 1.0f - 1e-7f);
                lobj = -__logf(pco);
                float dx = X - B0.x, dy = Y - B0.y, dob = OB - 1.0f;
                l2 = dx * dx + dy * dy + sc2 * (dw * dw + dh * dh) + dob * dob;
                omv = OB;
                int ridx = atomicAdd((int*)(ws + WS_CNT_F), 1);
                float* R = ws + WS_REC_F + ridx * 8;
                R[0] = (float)b; R[1] = fa_t; R[2] = (float)pc; R[3] = (float)mk;
                R[4] = X; R[5] = Y; R[6] = WR * sc; R[7] = HR * sc;
            } else {
                float oo = OB * objmask;
                if (objmask != 0.0f) {
                    float pco = fminf(OB, 1.0f - 1e-7f);
                    lobj = -__logf(1.0f - pco);
                }
                l2 = oo * oo;
                omv = oo;
            }
            ws[WS_OMV_F + (size_t)(b * A_ + a) * HW + pc] = omv;
        }
    }

    #pragma unroll
    for (int off = 32; off > 0; off >>= 1) {
        lxy += __shfl_down(lxy, off); lwh += __shfl_down(lwh, off);
        lobj += __shfl_down(lobj, off); l2 += __shfl_down(l2, off);
    }
    if ((t & 63) == 0) {
        redS[t >> 6][0] = lxy; redS[t >> 6][1] = lwh;
        redS[t >> 6][2] = lobj; redS[t >> 6][3] = l2;
    }
    __syncthreads();
    if (t == 0) {
        float s0 = 0, s1 = 0, s2 = 0, s3 = 0;
        #pragma unroll
        for (int wv = 0; wv < 8; wv++) {
            s0 += redS[wv][0]; s1 += redS[wv][1]; s2 += redS[wv][2]; s3 += redS[wv][3];
        }
        float* P = ws + WS_PART_F + (size_t)blk * 8;
        P[0] = s0; P[1] = s1; P[2] = s2; P[3] = 0.0f; P[4] = s3;
    }
}

// ---------------- writer: pure store-stream of dense out_m (zeros + obj ch from omv) ----------------
// slab float base = 6 + s*6460, base%4==2 -> head 2 floats, 1614 aligned float4, tail 2 floats
__global__ __launch_bounds__(256) void writer_kernel(const float* __restrict__ ws,
                                                     float* __restrict__ d_out) {
    const int t = threadIdx.x;
    const int s = blockIdx.x;                    // (b*3+a)*76 + j
    const int baj = s / F_, j = s - baj * F_;
    const float* om = ws + WS_OMV_F + (size_t)baj * HW + j * F_;
    float* slab = d_out + 6 + (size_t)s * SLAB;
    if (t == 0) { slab[0] = 0.0f; slab[1] = 0.0f; slab[6458] = 0.0f; slab[6459] = 0.0f; }
    float4* dst4 = (float4*)(slab + 2);
    for (int n = t; n < 1614; n += 256) {
        int f0 = 2 + 4 * n;
        int p = f0 / 85, r = f0 - 85 * p;
        float4 v = make_float4(0.0f, 0.0f, 0.0f, 0.0f);
        if (r >= 1 && r <= 4) ((float*)&v)[4 - r] = om[p];   // channel-4 slot
        dst4[n] = v;
    }
}

// ---------------- sparse: matched cells (<=800): f32 class dots + box-channel overwrite ----------------
__global__ __launch_bounds__(256) void sparse_kernel(const float* __restrict__ xin,
                                                     const float* __restrict__ conv_w,
                                                     float* __restrict__ ws,
                                                     float* __restrict__ d_out) {
    __shared__ float xcolS[256];
    __shared__ float rr[4][2];
    const int t = threadIdx.x;
    const int idx = blockIdx.x;
    float* P = ws + WS_PART_F + (size_t)(NCONV + idx) * 8;
    const int cnt = *(const int*)(ws + WS_CNT_F);
    if (idx >= cnt) { if (t < 8) P[t] = 0.0f; return; }
    const float* R = ws + WS_REC_F + idx * 8;
    const int b = (int)R[0], a = (int)R[1], p = (int)R[2], k = (int)R[3];
    const int j = p / F_, i = p - j * F_;
    xcolS[t] = xin[((size_t)b * CIN + t) * HW + p];
    __syncthreads();
    const float* Lr = ws + WS_LAB_F + (b * K_ + k) * 16;
    const int cl = (int)Lr[13];
    float* cell = d_out + 6 + (size_t)((b * A_ + a) * F_ + j) * SLAB + i * NCH;
    float lcls = 0.0f, l2 = 0.0f;
    if (t < 80) {
        const int o = a * NCH + 5 + t;
        const float4* wr4 = (const float4*)(conv_w + (size_t)o * CIN);
        float a0 = 0, a1 = 0, a2 = 0, a3 = 0;
        #pragma unroll 8
        for (int q = 0; q < 64; q++) {
            float4 wv = wr4[q];
            a0 = fmaf(wv.x, xcolS[q * 4 + 0], a0);
            a1 = fmaf(wv.y, xcolS[q * 4 + 1], a1);
            a2 = fmaf(wv.z, xcolS[q * 4 + 2], a2);
            a3 = fmaf(wv.w, xcolS[q * 4 + 3], a3);
        }
        float accv = ws[WS_BIAS_F + o] + ((a0 + a1) + (a2 + a3));
        float pc = sigm(accv);
        float tcv = (t == cl) ? 1.0f : 0.0f;
        lcls = bce_t(pc, tcv);
        float d = pc - tcv; l2 = d * d;
        cell[5 + t] = pc;
    } else if (t < 84) {
        cell[t - 80] = R[4 + (t - 80)];            // ch0=x, ch1=y, ch2=w*sc, ch3=h*sc (ch4 from writer)
    }
    #pragma unroll
    for (int off = 32; off > 0; off >>= 1) {
        lcls += __shfl_down(lcls, off); l2 += __shfl_down(l2, off);
    }
    if ((t & 63) == 0) { rr[t >> 6][0] = lcls; rr[t >> 6][1] = l2; }
    __syncthreads();
    if (t == 0) {
        P[0] = 0.0f; P[1] = 0.0f; P[2] = 0.0f;
        P[3] = rr[0][0] + rr[1][0] + rr[2][0] + rr[3][0];
        P[4] = rr[0][1] + rr[1][1] + rr[2][1] + rr[3][1];
    }
}

// ---------------- finish ----------------
__global__ void finish_kernel(const float* __restrict__ ws, float* __restrict__ d_out) {
    int t = threadIdx.x;
    const float* part = ws + WS_PART_F;
    float s0 = 0, s1 = 0, s2 = 0, s3 = 0, s4 = 0;
    for (int bidx = t; bidx < NROW; bidx += 256) {
        const float* P = part + (size_t)bidx * 8;
        s0 += P[0]; s1 += P[1]; s2 += P[2]; s3 += P[3]; s4 += P[4];
    }
    #pragma unroll
    for (int off = 32; off > 0; off >>= 1) {
        s0 += __shfl_down(s0, off); s1 += __shfl_down(s1, off);
        s2 += __shfl_down(s2, off); s3 += __shfl_down(s3, off);
        s4 += __shfl_down(s4, off);
    }
    __shared__ float red[4][5];
    if ((t & 63) == 0) {
        int w = t >> 6;
        red[w][0] = s0; red[w][1] = s1; red[w][2] = s2; red[w][3] = s3; red[w][4] = s4;
    }
    __syncthreads();
    if (t == 0) {
        float r0 = red[0][0] + red[1][0] + red[2][0] + red[3][0];
        float r1 = red[0][1] + red[1][1] + red[2][1] + red[3][1];
        float r2 = red[0][2] + red[1][2] + red[2][2] + red[3][2];
        float r3 = red[0][3] + red[1][3] + red[2][3] + red[3][3];
        float r4 = red[0][4] + red[1][4] + red[2][4] + red[3][4];
        d_out[0] = r0 + r1 + r2 + r3;
        d_out[1] = r0; d_out[2] = r1; d_out[3] = r2; d_out[4] = r3; d_out[5] = r4;
    }
}

extern "C" void kernel_launch(void* const* d_in, const int* in_sizes, int n_in,
                              void* d_out, int out_size, void* d_ws, size_t ws_size,
                              hipStream_t stream) {
    const float* xin    = (const float*)d_in[0];
    const float* labels = (const float*)d_in[1];
    const float* conv_w = (const float*)d_in[2];
    const float* conv_b = (const float*)d_in[3];
    float* out = (float*)d_out;
    float* ws  = (float*)d_ws;

    prep_kernel<<<3, 256, 0, stream>>>(conv_w, conv_b, labels, ws);
    convloss_kernel<<<NCONV, 512, 0, stream>>>(xin, ws);
    writer_kernel<<<B_ * A_ * F_, 256, 0, stream>>>(ws, out);
    sparse_kernel<<<NREC, 256, 0, stream>>>(xin, conv_w, ws, out);
    finish_kernel<<<1, 256, 0, stream>>>(ws, out);
}

// Round 9
// 232.062 us; speedup vs baseline: 1.1126x; 1.1126x over previous
//
#include <hip/hip_runtime.h>
#include <hip/hip_bf16.h>

#define B_   16
#define K_   50
#define CIN  256
#define F_   76
#define A_   3
#define NCH  85
#define OC   255
#define HW   (F_*F_)
#define SLAB (F_*NCH)            // 6460 floats per (b,a,j)

// ws float layout
#define WS_BIAS_F 0              // 256 (conv_b padded)
#define WS_LAB_F  256            // 16*50*16 = 12800
#define WS_W15P_F 13056          // 256*16 = 4096
#define WS_B15_F  17152          // 16
#define WS_CNT_F  17168          // 1 (int)
#define WS_REC_F  17184          // 800*8 = 6400
#define WS_PART_F 23584          // 1536*8 = 12288
#define WS_OMV_F  35872          // 16*3*5776 = 277248
#define WS_END_F  313120         // 1.25 MB

#define NTL   46                 // 128-position tiles per batch (46*128 >= 5776)
#define NCONV (B_*NTL)           // 736
#define NREC  800
#define NROW  (NCONV + NREC)     // 1536

__device__ __constant__ float AW9[9] = {1.25f, 2.0f, 4.125f, 3.75f, 7.75f, 7.375f, 14.5f, 19.5f, 46.625f};
__device__ __constant__ float AH9[9] = {1.625f, 3.75f, 2.875f, 7.625f, 5.625f, 14.875f, 11.25f, 24.75f, 40.75f};

__device__ __forceinline__ float sigm(float r) { return 1.0f / (1.0f + __expf(-r)); }
__device__ __forceinline__ float bce_t(float p, float tv) {
    float pc = fminf(fmaxf(p, 1e-12f), 1.0f - 1e-7f);
    return -(tv * __logf(pc) + (1.0f - tv) * __logf(1.0f - pc));
}

// ---------------- prep ----------------
// labrec: A0={tx,ty,tw,th} A1={valid, fa(-1 if not pos), fi, fj} B0={txv,tyv,logw,logh} B1={sc,cls,0,0}
__global__ void prep_kernel(const float* __restrict__ conv_w, const float* __restrict__ conv_b,
                            const float* __restrict__ labels, float* __restrict__ ws) {
    int bid = blockIdx.x, t = threadIdx.x;
    if (bid == 0) {
        ws[WS_BIAS_F + t] = (t < OC) ? conv_b[t] : 0.0f;
    } else if (bid == 1) {
        for (int idx = t; idx < B_ * K_; idx += 256) {
            const float* L = labels + idx * 5;
            float cls = L[0], xc = L[1], yc = L[2], wl = L[3], hl = L[4];
            float ssum = cls + xc + yc + wl + hl;
            float validf = (ssum > 0.0f) ? 1.0f : 0.0f;
            float tx = xc * F_, ty = yc * F_, tw = wl * F_, th = hl * F_;
            int ii = (int)tx, jj = (int)ty;
            float tarea = tw * th;
            float best = -1.0f; int bn = 0;
            #pragma unroll
            for (int n = 0; n < 9; n++) {
                float inter = fminf(tw, AW9[n]) * fminf(th, AH9[n]);
                float iou = inter / (tarea + AW9[n] * AH9[n] - inter);
                if (iou > best) { best = iou; bn = n; }
            }
            int a = bn % 3;
            bool self = (validf != 0.0f) && (bn < 3);
            float* R = ws + WS_LAB_F + idx * 16;
            R[0] = tx; R[1] = ty; R[2] = tw; R[3] = th;
            R[4] = validf; R[5] = self ? (float)a : -1.0f; R[6] = (float)ii; R[7] = (float)jj;
            R[8] = tx - (float)ii; R[9] = ty - (float)jj;
            R[10] = __logf(tw / AW9[a] + 1e-16f);
            R[11] = __logf(th / AH9[a] + 1e-16f);
            R[12] = sqrtf(2.0f - tarea / (float)HW);
            R[13] = cls; R[14] = 0.0f; R[15] = 0.0f;
        }
    } else { // W15 padded f32 [c][16] + bias15 + counter reset
        for (int idx = t; idx < 4096; idx += 256) {
            int c = idx >> 4, r = idx & 15;
            float v = 0.0f;
            if (r < 15) v = conv_w[((r / 5) * NCH + (r % 5)) * CIN + c];
            ws[WS_W15P_F + idx] = v;
        }
        if (t < 16) ws[WS_B15_F + t] = (t < 15) ? conv_b[(t / 5) * NCH + (t % 5)] : 0.0f;
        if (t == 16) *(int*)(ws + WS_CNT_F) = 0;
    }
}

// ---------------- convloss: 4-way channel-split conv (regs) + per-(pos,anchor) losses ----------------
// Block = (b, tile of 128 positions); 512 threads; quarter q (WAVE-UNIFORM via readfirstlane
// -> W rows become scalar s_loads) handles channels [64q, 64q+64).
__global__ __launch_bounds__(512) void convloss_kernel(const float* __restrict__ xin,
                                                       float* __restrict__ ws) {
    __shared__ float4 LAB[K_ * 4];        // 3200 B
    __shared__ float accS[4][128][17];    // 34816 B (stride 17 -> conflict-free)
    __shared__ float redS[8][4];

    const int t = threadIdx.x;
    const int blk = blockIdx.x;
    const int b = blk / NTL, tile = blk - b * NTL;
    const int ph = t & 127;
    const int q  = __builtin_amdgcn_readfirstlane(t) >> 7;   // wave-uniform quarter
    const int p0 = tile * 128 + ph;
    const int p = (p0 < HW) ? p0 : HW - 1;

    if (t < K_ * 4) LAB[t] = ((const float4*)(ws + WS_LAB_F + b * (K_ * 16)))[t];

    // ---- conv: this thread's 64-channel quarter, software-pipelined 8-wide ----
    const float* xp = xin + (size_t)b * CIN * HW + (size_t)q * 64 * HW + p;
    const float* Wp = ws + WS_W15P_F + q * 64 * 16;

    float acc[15];
    #pragma unroll
    for (int r = 0; r < 15; r++) acc[r] = 0.0f;

    float xv[8];
    #pragma unroll
    for (int u = 0; u < 8; u++) xv[u] = xp[(size_t)u * HW];
    #pragma unroll 1
    for (int c8 = 0; c8 < 8; c8++) {
        float xn[8];
        const int cnx = (c8 < 7) ? (c8 + 1) : 7;
        #pragma unroll
        for (int u = 0; u < 8; u++) xn[u] = xp[(size_t)(cnx * 8 + u) * HW];
        #pragma unroll
        for (int u = 0; u < 8; u++) {
            const float xvu = xv[u];
            const float* wrow = Wp + (c8 * 8 + u) * 16;   // uniform -> scalar loads
            #pragma unroll
            for (int r = 0; r < 15; r++) acc[r] = fmaf(xvu, wrow[r], acc[r]);
        }
        #pragma unroll
        for (int u = 0; u < 8; u++) xv[u] = xn[u];
    }

    #pragma unroll
    for (int r = 0; r < 15; r++) accS[q][ph][r] = acc[r];
    __syncthreads();

    // ---- loss phase: one (pos, anchor) cell per thread, t < 384 ----
    float lxy = 0.0f, lwh = 0.0f, lobj = 0.0f, l2 = 0.0f;
    if (t < 384) {
        const int a = t >> 7, pp = t & 127;
        const int pc = tile * 128 + pp;
        if (pc < HW) {
            float c5[5];
            #pragma unroll
            for (int r = 0; r < 5; r++)
                c5[r] = accS[0][pp][a * 5 + r] + accS[1][pp][a * 5 + r]
                      + accS[2][pp][a * 5 + r] + accS[3][pp][a * 5 + r]
                      + ws[WS_B15_F + a * 5 + r];
            const int j = pc / F_, i = pc - j * F_;
            const float fi_t = (float)i, fj_t = (float)j, fa_t = (float)a;
            const float X = sigm(c5[0]), Y = sigm(c5[1]);
            const float WR = c5[2], HR = c5[3], OB = sigm(c5[4]);
            const float PX = X + fi_t, PY = Y + fj_t;
            const float pw_ = __expf(WR) * AW9[a], ph_ = __expf(HR) * AH9[a];
            const float hpw = pw_ * 0.5f, hph = ph_ * 0.5f, arp = pw_ * ph_;

            float maxiou = 0.0f; int mk = -1;
            #pragma unroll 2
            for (int k = 0; k < K_; k++) {
                float4 A0 = LAB[4 * k], A1 = LAB[4 * k + 1];
                float tx = A0.x, ty = A0.y, tw = A0.z, th = A0.w;
                float tlx = fmaxf(PX - hpw, tx - tw * 0.5f);
                float tly = fmaxf(PY - hph, ty - th * 0.5f);
                float brx = fminf(PX + hpw, tx + tw * 0.5f);
                float bry = fminf(PY + hph, ty + th * 0.5f);
                float iw = brx - tlx, ih = bry - tly;
                float inter = (iw > 0.0f && ih > 0.0f) ? iw * ih : 0.0f;
                float iou = __fdividef(inter, arp + tw * th - inter);
                iou = (A1.x != 0.0f) ? iou : 0.0f;
                maxiou = fmaxf(maxiou, iou);
                bool match = (A1.y == fa_t) & (A1.z == fi_t) & (A1.w == fj_t);
                mk = match ? k : mk;
            }
            float objmask = (maxiou > 0.7f) ? 0.0f : 1.0f;
            float omv;
            if (mk >= 0) {
                float4 B0 = LAB[4 * mk + 2];
                float4 B1 = LAB[4 * mk + 3];
                float sc = B1.x, sc2 = sc * sc;
                lxy = (bce_t(X, B0.x) + bce_t(Y, B0.y)) * sc2;
                float dw = WR - B0.z, dh = HR - B0.w;
                lwh = 0.5f * sc2 * (dw * dw + dh * dh);
                float pco = fminf(fmaxf(OB, 1e-12f), 1.0f - 1e-7f);
                lobj = -__logf(pco);
                float dx = X - B0.x, dy = Y - B0.y, dob = OB - 1.0f;
                l2 = dx * dx + dy * dy + sc2 * (dw * dw + dh * dh) + dob * dob;
                omv = OB;
                int ridx = atomicAdd((int*)(ws + WS_CNT_F), 1);
                float* R = ws + WS_REC_F + ridx * 8;
                R[0] = (float)b; R[1] = fa_t; R[2] = (float)pc; R[3] = (float)mk;
                R[4] = X; R[5] = Y; R[6] = WR * sc; R[7] = HR * sc;
            } else {
                float oo = OB * objmask;
                if (objmask != 0.0f) {
                    float pco = fminf(OB, 1.0f - 1e-7f);
                    lobj = -__logf(1.0f - pco);
                }
                l2 = oo * oo;
                omv = oo;
            }
            ws[WS_OMV_F + (size_t)(b * A_ + a) * HW + pc] = omv;
        }
    }

    #pragma unroll
    for (int off = 32; off > 0; off >>= 1) {
        lxy += __shfl_down(lxy, off); lwh += __shfl_down(lwh, off);
        lobj += __shfl_down(lobj, off); l2 += __shfl_down(l2, off);
    }
    if ((t & 63) == 0) {
        redS[t >> 6][0] = lxy; redS[t >> 6][1] = lwh;
        redS[t >> 6][2] = lobj; redS[t >> 6][3] = l2;
    }
    __syncthreads();
    if (t == 0) {
        float s0 = 0, s1 = 0, s2 = 0, s3 = 0;
        #pragma unroll
        for (int wv = 0; wv < 8; wv++) {
            s0 += redS[wv][0]; s1 += redS[wv][1]; s2 += redS[wv][2]; s3 += redS[wv][3];
        }
        float* P = ws + WS_PART_F + (size_t)blk * 8;
        P[0] = s0; P[1] = s1; P[2] = s2; P[3] = 0.0f; P[4] = s3;
    }
}

// ---------------- writer: pure store-stream of dense out_m (zeros + obj ch from omv) ----------------
// slab float base = 6 + s*6460, base%4==2 -> head 2 floats, 1614 aligned float4, tail 2 floats
__global__ __launch_bounds__(256) void writer_kernel(const float* __restrict__ ws,
                                                     float* __restrict__ d_out) {
    const int t = threadIdx.x;
    const int s = blockIdx.x;                    // (b*3+a)*76 + j
    const int baj = s / F_, j = s - baj * F_;
    const float* om = ws + WS_OMV_F + (size_t)baj * HW + j * F_;
    float* slab = d_out + 6 + (size_t)s * SLAB;
    if (t == 0) { slab[0] = 0.0f; slab[1] = 0.0f; slab[6458] = 0.0f; slab[6459] = 0.0f; }
    float4* dst4 = (float4*)(slab + 2);
    for (int n = t; n < 1614; n += 256) {
        int f0 = 2 + 4 * n;
        int p = f0 / 85, r = f0 - 85 * p;
        float4 v = make_float4(0.0f, 0.0f, 0.0f, 0.0f);
        if (r >= 1 && r <= 4) ((float*)&v)[4 - r] = om[p];   // channel-4 slot
        dst4[n] = v;
    }
}

// ---------------- sparse: matched cells (<=800): f32 class dots + box-channel overwrite ----------------
__global__ __launch_bounds__(256) void sparse_kernel(const float* __restrict__ xin,
                                                     const float* __restrict__ conv_w,
                                                     float* __restrict__ ws,
                                                     float* __restrict__ d_out) {
    __shared__ float xcolS[256];
    __shared__ float rr[4][2];
    const int t = threadIdx.x;
    const int idx = blockIdx.x;
    float* P = ws + WS_PART_F + (size_t)(NCONV + idx) * 8;
    const int cnt = *(const int*)(ws + WS_CNT_F);
    if (idx >= cnt) { if (t < 8) P[t] = 0.0f; return; }
    const float* R = ws + WS_REC_F + idx * 8;
    const int b = (int)R[0], a = (int)R[1], p = (int)R[2], k = (int)R[3];
    const int j = p / F_, i = p - j * F_;
    xcolS[t] = xin[((size_t)b * CIN + t) * HW + p];
    __syncthreads();
    const float* Lr = ws + WS_LAB_F + (b * K_ + k) * 16;
    const int cl = (int)Lr[13];
    float* cell = d_out + 6 + (size_t)((b * A_ + a) * F_ + j) * SLAB + i * NCH;
    float lcls = 0.0f, l2 = 0.0f;
    if (t < 80) {
        const int o = a * NCH + 5 + t;
        const float4* wr4 = (const float4*)(conv_w + (size_t)o * CIN);
        float a0 = 0, a1 = 0, a2 = 0, a3 = 0;
        #pragma unroll 8
        for (int q = 0; q < 64; q++) {
            float4 wv = wr4[q];
            a0 = fmaf(wv.x, xcolS[q * 4 + 0], a0);
            a1 = fmaf(wv.y, xcolS[q * 4 + 1], a1);
            a2 = fmaf(wv.z, xcolS[q * 4 + 2], a2);
            a3 = fmaf(wv.w, xcolS[q * 4 + 3], a3);
        }
        float accv = ws[WS_BIAS_F + o] + ((a0 + a1) + (a2 + a3));
        float pc = sigm(accv);
        float tcv = (t == cl) ? 1.0f : 0.0f;
        lcls = bce_t(pc, tcv);
        float d = pc - tcv; l2 = d * d;
        cell[5 + t] = pc;
    } else if (t < 84) {
        cell[t - 80] = R[4 + (t - 80)];            // ch0=x, ch1=y, ch2=w*sc, ch3=h*sc (ch4 from writer)
    }
    #pragma unroll
    for (int off = 32; off > 0; off >>= 1) {
        lcls += __shfl_down(lcls, off); l2 += __shfl_down(l2, off);
    }
    if ((t & 63) == 0) { rr[t >> 6][0] = lcls; rr[t >> 6][1] = l2; }
    __syncthreads();
    if (t == 0) {
        P[0] = 0.0f; P[1] = 0.0f; P[2] = 0.0f;
        P[3] = rr[0][0] + rr[1][0] + rr[2][0] + rr[3][0];
        P[4] = rr[0][1] + rr[1][1] + rr[2][1] + rr[3][1];
    }
}

// ---------------- finish ----------------
__global__ void finish_kernel(const float* __restrict__ ws, float* __restrict__ d_out) {
    int t = threadIdx.x;
    const float* part = ws + WS_PART_F;
    float s0 = 0, s1 = 0, s2 = 0, s3 = 0, s4 = 0;
    for (int bidx = t; bidx < NROW; bidx += 256) {
        const float* P = part + (size_t)bidx * 8;
        s0 += P[0]; s1 += P[1]; s2 += P[2]; s3 += P[3]; s4 += P[4];
    }
    #pragma unroll
    for (int off = 32; off > 0; off >>= 1) {
        s0 += __shfl_down(s0, off); s1 += __shfl_down(s1, off);
        s2 += __shfl_down(s2, off); s3 += __shfl_down(s3, off);
        s4 += __shfl_down(s4, off);
    }
    __shared__ float red[4][5];
    if ((t & 63) == 0) {
        int w = t >> 6;
        red[w][0] = s0; red[w][1] = s1; red[w][2] = s2; red[w][3] = s3; red[w][4] = s4;
    }
    __syncthreads();
    if (t == 0) {
        float r0 = red[0][0] + red[1][0] + red[2][0] + red[3][0];
        float r1 = red[0][1] + red[1][1] + red[2][1] + red[3][1];
        float r2 = red[0][2] + red[1][2] + red[2][2] + red[3][2];
        float r3 = red[0][3] + red[1][3] + red[2][3] + red[3][3];
        float r4 = red[0][4] + red[1][4] + red[2][4] + red[3][4];
        d_out[0] = r0 + r1 + r2 + r3;
        d_out[1] = r0; d_out[2] = r1; d_out[3] = r2; d_out[4] = r3; d_out[5] = r4;
    }
}

extern "C" void kernel_launch(void* const* d_in, const int* in_sizes, int n_in,
                              void* d_out, int out_size, void* d_ws, size_t ws_size,
                              hipStream_t stream) {
    const float* xin    = (const float*)d_in[0];
    const float* labels = (const float*)d_in[1];
    const float* conv_w = (const float*)d_in[2];
    const float* conv_b = (const float*)d_in[3];
    float* out = (float*)d_out;
    float* ws  = (float*)d_ws;

    prep_kernel<<<3, 256, 0, stream>>>(conv_w, conv_b, labels, ws);
    convloss_kernel<<<NCONV, 512, 0, stream>>>(xin, ws);
    writer_kernel<<<B_ * A_ * F_, 256, 0, stream>>>(ws, out);
    sparse_kernel<<<NREC, 256, 0, stream>>>(xin, conv_w, ws, out);
    finish_kernel<<<1, 256, 0, stream>>>(ws, out);
}